// Round 3
// baseline (186.831 us; speedup 1.0000x reference)
//
#include <hip/hip_runtime.h>

typedef short short8 __attribute__((ext_vector_type(8)));
typedef float f32x4 __attribute__((ext_vector_type(4)));
typedef unsigned short u16;
typedef __attribute__((address_space(3))) unsigned lds_u32_t;
typedef __attribute__((address_space(1))) const unsigned glb_u32_t;

namespace {
constexpr int NIMG = 16;
constexpr int CIN  = 256;
constexpr int HIMG = 56;
constexpr int WIMG = 56;
constexpr int KOUT = 256;
constexpr int PIX  = HIMG * WIMG;          // 3136
constexpr int HPAD = 58;
constexpr int PP   = HPAD * HPAD;          // 3364
constexpr int TILES = 26;                  // 26*128 = 3328 >= 3246
constexpr int NX   = NIMG * CIN * PIX;     // 12,845,056
constexpr int NWEL = KOUT * CIN * 9;       // 589,824
constexpr int XQ_HALVES = NIMG * 32 * PP * 8;   // 13,778,944
constexpr int MAXB = XQ_HALVES - 8;
constexpr int CHUNK = 8 * PIX;             // 25088 elements per (n, c-octet)
constexpr int XBLK = NIMG * 32;            // 512 fused x-quant blocks
constexpr int WB   = 64;                   // weight-quant blocks
}

// ---------------------------------------------------------------------------
// Fused BFP-quant + layout transform, one launch:
//   blocks [0, XBLK)        : x path. Block = one (n, 8-channel octet) =
//     25088 consecutive flat elements. Each thread quantizes whole 36-elem
//     groups straight from global (9 aligned float4 each; groups straddling
//     the octet boundary are recomputed by both neighbors, writes guarded),
//     stages bf16 into a flat 50 KB LDS tile, then writes the chunked padded
//     xq2 layout with coalesced short8 stores + zeroes its own halo ring.
//   blocks [XBLK, XBLK+WB)  : BFP quantize weights -> wt3[rs][csp][kc][kout][8]
// ---------------------------------------------------------------------------
__global__ __launch_bounds__(256) void quant_fused(
        const float* __restrict__ x, u16* __restrict__ xq2,
        const float* __restrict__ wsrc, u16* __restrict__ wt3) {
    __shared__ u16 ot[CHUNK];                  // [cl*3136 + p] bf16, 50 KB
    const int b = blockIdx.x;
    const int t = threadIdx.x;

    if (b < XBLK) {
        const long s  = (long)b * CHUNK;       // first flat element of block
        const int  g0 = (int)(s / 36);
        const int  g1 = (int)((s + CHUNK - 1) / 36);

        // halo ring zero (independent of LDS; overlaps with loads)
        if (t < 228) {
            int ph, pw;
            if (t < 58)       { ph = 0;  pw = t; }
            else if (t < 116) { ph = 57; pw = t - 58; }
            else { int r = t - 116; ph = 1 + (r >> 1); pw = (r & 1) * 57; }
            *(uint4*)(xq2 + ((size_t)b * PP + ph * HPAD + pw) * 8) =
                make_uint4(0, 0, 0, 0);
        }

        for (int g = g0 + t; g <= g1; g += 256) {
            const long e0 = (long)g * 36;
            float v[36];
            if (e0 + 36 <= (long)NX) {
                const float4* p4 = (const float4*)(x + e0);
#pragma unroll
                for (int j = 0; j < 9; j++) {
                    float4 q4 = p4[j];
                    v[4*j+0] = q4.x; v[4*j+1] = q4.y;
                    v[4*j+2] = q4.z; v[4*j+3] = q4.w;
                }
            } else {                           // single global-tail group
                for (int j = 0; j < 36; j++)
                    v[j] = (e0 + j < (long)NX) ? x[e0 + j] : 0.f;
            }
            float ma = 0.f;
#pragma unroll
            for (int j = 0; j < 36; j++) ma = fmaxf(ma, fabsf(v[j]));
            float scale = 0.f, rinv = 0.f;
            if (ma != 0.f) {
                float e = floorf(log2f(ma));
                scale = exp2f(e - 7.f);
                rinv  = exp2f(7.f - e);
            }
            const long o = e0 - s;             // even; pairs never straddle
#pragma unroll
            for (int j = 0; j < 36; j += 2) {
                float qa = fminf(fmaxf(rintf(v[j]   * rinv), -128.f), 127.f) * scale;
                float qb = fminf(fmaxf(rintf(v[j+1] * rinv), -128.f), 127.f) * scale;
                uint pk = (__float_as_uint(qa) >> 16)
                        | ((__float_as_uint(qb) >> 16) << 16);
                long oo = o + j;
                if (oo >= 0 && oo < CHUNK)
                    *(uint*)&ot[oo] = pk;      // aligned b32 (oo even)
            }
        }
        __syncthreads();

        // interior write-out: coalesced short8, conflict-free scalar LDS reads
        for (int p = t; p < PIX; p += 256) {
            short8 o8;
#pragma unroll
            for (int cl = 0; cl < 8; cl++)
                o8[cl] = (short)ot[cl * PIX + p];
            int ph = p / WIMG + 1, pw = p % WIMG + 1;
            *(short8*)(xq2 + ((size_t)b * PP + ph * HPAD + pw) * 8) = o8;
        }
    } else {
        int g = (b - XBLK) * 256 + t;          // < 16384
        int base = g * 36;
        float v[36];
        const float4* p4 = (const float4*)(wsrc + base);
#pragma unroll
        for (int j = 0; j < 9; j++) {
            float4 tt = p4[j];
            v[4*j+0] = tt.x; v[4*j+1] = tt.y; v[4*j+2] = tt.z; v[4*j+3] = tt.w;
        }
        float ma = 0.f;
#pragma unroll
        for (int j = 0; j < 36; j++) ma = fmaxf(ma, fabsf(v[j]));
        float scale = 0.f, rinv = 0.f;
        if (ma != 0.f) {
            float e = floorf(log2f(ma));
            scale = exp2f(e - 7.f);
            rinv  = exp2f(7.f - e);
        }
        int k  = g >> 6;
        int c0 = (g & 63) * 4;
#pragma unroll
        for (int j = 0; j < 36; j++) {
            float q = rintf(v[j] * rinv);
            q = fminf(fmaxf(q, -128.f), 127.f) * scale;
            int c  = c0 + j / 9;
            int rs = j % 9;
            // wt3[rs][c>>6][(c>>3)&7][k][c&7]
            int idx = ((((rs * 4 + (c >> 6)) * 8 + ((c >> 3) & 7)) * KOUT) + k) * 8 + (c & 7);
            wt3[idx] = (u16)(__float_as_uint(q) >> 16);
        }
    }
}

// ---------------------------------------------------------------------------
// Implicit-GEMM conv, 72-phase triple-buffered pipeline (T3+T4+T5):
//   - each old BK=64 stage split into two BK=32 half-stages; accumulation
//     order (csp -> rs -> kc ascending) identical to before (bit-exact).
//   - 3 LDS buffers of (8 KB A + 8 KB B) = 48 KB total -> 3 blocks/CU.
//   - per phase h per wave: 8 ds_read_b128, 16 MFMA (setprio-wrapped),
//     then ISSUE(h+2) = 4 global_load_lds into buf[(h+2)%3].
//   - phase top: s_waitcnt vmcnt(4) (phase h's loads retired, h+1's 4 stay
//     in flight across the barrier) -> single barrier per phase, no drain.
// ---------------------------------------------------------------------------
#define ISSUE3(csp_, rs_, sub_, qb_)                                           \
    {                                                                          \
        const int xoff8_ = (((rs_) / 3) * HPAD + ((rs_) % 3)) * 8;             \
        const int sA_ = ((rs_) * 4 + (csp_)) * 16384 + (sub_) * 8192;          \
        const int sB_ = ((csp_) * 8 + (sub_) * 4) * PP * 8;                    \
        _Pragma("unroll")                                                      \
        for (int hl = 0; hl < 2; hl++) {                                       \
            __builtin_amdgcn_global_load_lds(                                  \
                (glb_u32_t*)(wt3 + sA_ + hl * 512 + aLw),                      \
                (lds_u32_t*)(lA3[qb_] + hl * 512 + dstw),                      \
                16, 0, 0);                                                     \
            int bi_ = bBw + sB_ + xoff8_ + hl * 512;                           \
            bi_ = min(bi_, MAXB);     /* only invalid-col tail lanes clamp */  \
            __builtin_amdgcn_global_load_lds(                                  \
                (glb_u32_t*)(xq2 + bi_),                                       \
                (lds_u32_t*)(lB3[qb_] + hl * 512 + dstw),                      \
                16, 0, 0);                                                     \
        }                                                                      \
    }

__global__ __launch_bounds__(256) void conv_kernel(
        const u16* __restrict__ xq2, const u16* __restrict__ wt3,
        const float* __restrict__ bias, float* __restrict__ out) {
    __shared__ u16 lA3[3][4096];   // [buf][kc(4)][kout-row(128)][8] = 3 x 8 KB
    __shared__ u16 lB3[3][4096];   // [buf][kc(4)][col(128)][8]      = 3 x 8 KB

    const int tid  = threadIdx.x;
    const int lane = tid & 63;
    const int wv   = tid >> 6;
    const int bx   = blockIdx.x;
    const int n    = bx / TILES;
    const int t0   = (bx % TILES) * 128;
    const int k0   = blockIdx.y * 128;

    // global bases (u16 half-index); per phase: kc = sub*4 + wv
    const int aLw  = (k0 + lane) * 8 + wv * 2048;          // + sA_/hl consts
    const int bBw  = ((n * 32 + wv) * PP + t0 + lane) * 8; // + sB_/xoff/hl
    const int dstw = wv * 1024 + lane * 8;                 // LDS dest (halves)

    const int frow = lane & 15;
    const int fkk  = lane >> 4;
    const int fAo = (fkk * 128 + (wv >> 1) * 64 + frow) * 8;
    const int fBo = (fkk * 128 + (wv & 1) * 64 + frow) * 8;

    f32x4 acc[4][4] = {};

    // prologue: phases 0 and 1 into buffers 0 and 1
    ISSUE3(0, 0, 0, 0);
    ISSUE3(0, 0, 1, 1);

#pragma unroll
    for (int h = 0; h < 72; h++) {
        // phase h's 4 loads retired; phase h+1's 4 remain in flight
        if (h < 71) asm volatile("s_waitcnt vmcnt(4)" ::: "memory");
        else        asm volatile("s_waitcnt vmcnt(0)" ::: "memory");
        __builtin_amdgcn_s_barrier();        // all waves' phase-h loads landed
        __builtin_amdgcn_sched_barrier(0);   // no ds_read hoisted above barrier

        const int hb = h % 3;
        short8 af[4], bf[4];
#pragma unroll
        for (int i = 0; i < 4; i++)
            af[i] = *(const short8*)(lA3[hb] + fAo + i * 128);
#pragma unroll
        for (int j = 0; j < 4; j++)
            bf[j] = *(const short8*)(lB3[hb] + fBo + j * 128);

        __builtin_amdgcn_s_setprio(1);
#pragma unroll
        for (int i = 0; i < 4; i++)
#pragma unroll
            for (int j = 0; j < 4; j++)
                acc[i][j] = __builtin_amdgcn_mfma_f32_16x16x32_bf16(
                    af[i], bf[j], acc[i][j], 0, 0, 0);
        __builtin_amdgcn_s_setprio(0);
        __builtin_amdgcn_sched_barrier(0);   // ISSUE stays after this point

        if (h + 2 < 72) {
            const int h2 = h + 2;
            ISSUE3(h2 / 18, (h2 / 2) % 9, h2 & 1, h2 % 3);
        }
    }

    // epilogue: rows = outch, cols = padded pixel t0+col; skip invalid cols
    const int kbase = k0 + (wv >> 1) * 64 + fkk * 4;
    const int mbase = (wv & 1) * 64 + frow;
#pragma unroll
    for (int j = 0; j < 4; j++) {
        int ppp = t0 + mbase + j * 16;
        int h = ppp / HPAD, w = ppp % HPAD;
        if (w < WIMG && h < HIMG) {
            float* ob = out + (size_t)n * KOUT * PIX + h * WIMG + w;
#pragma unroll
            for (int i = 0; i < 4; i++) {
                int kch = kbase + i * 16;
#pragma unroll
                for (int r = 0; r < 4; r++)
                    ob[(size_t)(kch + r) * PIX] = acc[i][j][r] + bias[kch + r];
            }
        }
    }
}

// ---------------------------------------------------------------------------
extern "C" void kernel_launch(void* const* d_in, const int* in_sizes, int n_in,
                              void* d_out, int out_size, void* d_ws, size_t ws_size,
                              hipStream_t stream) {
    const float* x   = (const float*)d_in[0];
    const float* wgt = (const float*)d_in[1];
    const float* bs  = (const float*)d_in[2];
    float* out = (float*)d_out;

    u16* xq2 = (u16*)d_ws;                 // 27.56 MB chunked padded activations
    u16* wt3 = xq2 + XQ_HALVES;            // 1.18 MB  staged weight layout

    quant_fused<<<XBLK + WB, 256, 0, stream>>>(x, xq2, wgt, wt3);
    conv_kernel<<<dim3(NIMG * TILES, 2), 256, 0, stream>>>(xq2, wt3, bs, out);
}

// Round 4
// 163.753 us; speedup vs baseline: 1.1409x; 1.1409x over previous
//
#include <hip/hip_runtime.h>

typedef short short8 __attribute__((ext_vector_type(8)));
typedef float f32x4 __attribute__((ext_vector_type(4)));
typedef unsigned short u16;
typedef __attribute__((address_space(3))) unsigned lds_u32_t;
typedef __attribute__((address_space(1))) const unsigned glb_u32_t;

namespace {
constexpr int NIMG = 16;
constexpr int CIN  = 256;
constexpr int HIMG = 56;
constexpr int WIMG = 56;
constexpr int KOUT = 256;
constexpr int PIX  = HIMG * WIMG;          // 3136
constexpr int HPAD = 58;
constexpr int PP   = HPAD * HPAD;          // 3364
constexpr int TILES = 26;                  // 26*128 = 3328 >= 3246
constexpr int NX   = NIMG * CIN * PIX;     // 12,845,056
constexpr int NWEL = KOUT * CIN * 9;       // 589,824
constexpr int XQ_HALVES = NIMG * 32 * PP * 8;   // 13,778,944
constexpr int CHUNK = 8 * PIX;             // 25088 elements per (n, c-octet)
constexpr int XBLK = NIMG * 32;            // 512 fused x-quant blocks
constexpr int WB   = 64;                   // weight-quant blocks
}

// ---------------------------------------------------------------------------
// Fused BFP-quant + layout transform, one launch (unchanged from round 2):
//   blocks [0, XBLK)        : x -> xq2 chunked padded bf16 + halo
//   blocks [XBLK, XBLK+WB)  : weights -> wt3[rs][csp][kc][kout][8]
// ---------------------------------------------------------------------------
__global__ __launch_bounds__(256) void quant_fused(
        const float* __restrict__ x, u16* __restrict__ xq2,
        const float* __restrict__ wsrc, u16* __restrict__ wt3) {
    __shared__ u16 ot[CHUNK];                  // [cl*3136 + p] bf16, 50 KB
    const int b = blockIdx.x;
    const int t = threadIdx.x;

    if (b < XBLK) {
        const long s  = (long)b * CHUNK;       // first flat element of block
        const int  g0 = (int)(s / 36);
        const int  g1 = (int)((s + CHUNK - 1) / 36);

        // halo ring zero (independent of LDS; overlaps with loads)
        if (t < 228) {
            int ph, pw;
            if (t < 58)       { ph = 0;  pw = t; }
            else if (t < 116) { ph = 57; pw = t - 58; }
            else { int r = t - 116; ph = 1 + (r >> 1); pw = (r & 1) * 57; }
            *(uint4*)(xq2 + ((size_t)b * PP + ph * HPAD + pw) * 8) =
                make_uint4(0, 0, 0, 0);
        }

        for (int g = g0 + t; g <= g1; g += 256) {
            const long e0 = (long)g * 36;
            float v[36];
            if (e0 + 36 <= (long)NX) {
                const float4* p4 = (const float4*)(x + e0);
#pragma unroll
                for (int j = 0; j < 9; j++) {
                    float4 q4 = p4[j];
                    v[4*j+0] = q4.x; v[4*j+1] = q4.y;
                    v[4*j+2] = q4.z; v[4*j+3] = q4.w;
                }
            } else {                           // single global-tail group
                for (int j = 0; j < 36; j++)
                    v[j] = (e0 + j < (long)NX) ? x[e0 + j] : 0.f;
            }
            float ma = 0.f;
#pragma unroll
            for (int j = 0; j < 36; j++) ma = fmaxf(ma, fabsf(v[j]));
            float scale = 0.f, rinv = 0.f;
            if (ma != 0.f) {
                float e = floorf(log2f(ma));
                scale = exp2f(e - 7.f);
                rinv  = exp2f(7.f - e);
            }
            const long o = e0 - s;             // even; pairs never straddle
#pragma unroll
            for (int j = 0; j < 36; j += 2) {
                float qa = fminf(fmaxf(rintf(v[j]   * rinv), -128.f), 127.f) * scale;
                float qb = fminf(fmaxf(rintf(v[j+1] * rinv), -128.f), 127.f) * scale;
                uint pk = (__float_as_uint(qa) >> 16)
                        | ((__float_as_uint(qb) >> 16) << 16);
                long oo = o + j;
                if (oo >= 0 && oo < CHUNK)
                    *(uint*)&ot[oo] = pk;      // aligned b32 (oo even)
            }
        }
        __syncthreads();

        // interior write-out: coalesced short8, conflict-free scalar LDS reads
        for (int p = t; p < PIX; p += 256) {
            short8 o8;
#pragma unroll
            for (int cl = 0; cl < 8; cl++)
                o8[cl] = (short)ot[cl * PIX + p];
            int ph = p / WIMG + 1, pw = p % WIMG + 1;
            *(short8*)(xq2 + ((size_t)b * PP + ph * HPAD + pw) * 8) = o8;
        }
    } else {
        int g = (b - XBLK) * 256 + t;          // < 16384
        int base = g * 36;
        float v[36];
        const float4* p4 = (const float4*)(wsrc + base);
#pragma unroll
        for (int j = 0; j < 9; j++) {
            float4 tt = p4[j];
            v[4*j+0] = tt.x; v[4*j+1] = tt.y; v[4*j+2] = tt.z; v[4*j+3] = tt.w;
        }
        float ma = 0.f;
#pragma unroll
        for (int j = 0; j < 36; j++) ma = fmaxf(ma, fabsf(v[j]));
        float scale = 0.f, rinv = 0.f;
        if (ma != 0.f) {
            float e = floorf(log2f(ma));
            scale = exp2f(e - 7.f);
            rinv  = exp2f(7.f - e);
        }
        int k  = g >> 6;
        int c0 = (g & 63) * 4;
#pragma unroll
        for (int j = 0; j < 36; j++) {
            float q = rintf(v[j] * rinv);
            q = fminf(fmaxf(q, -128.f), 127.f) * scale;
            int c  = c0 + j / 9;
            int rs = j % 9;
            // wt3[rs][c>>6][(c>>3)&7][k][c&7]
            int idx = ((((rs * 4 + (c >> 6)) * 8 + ((c >> 3) & 7)) * KOUT) + k) * 8 + (c & 7);
            wt3[idx] = (u16)(__float_as_uint(q) >> 16);
        }
    }
}

// ---------------------------------------------------------------------------
// Implicit-GEMM conv, LDS-traffic-minimized structure:
//   - A (weights) bypasses LDS entirely: each lane's MFMA A-fragment is 16
//     contiguous bytes in wt3 -> direct global->VGPR loads, 3 rotating banks
//     (depth-3 prefetch, counted vmcnt(8)), redundancy served by L1/L2.
//   - B (activations) staged once per csp-slab as a 32 KB pixel window
//     [octet(8)][pix(256)][8]; all 9 taps x 2 subs read shifted frags from
//     the same window. 4 stages total -> 8 barriers + 4 vmcnt(0) drains per
//     block (vs 72 of each before). LDS writes drop 4.5x, ds_reads 2x.
//   - chunk order (csp -> rs -> sub) and MFMA operand sequence identical to
//     previous rounds -> bit-exact output.
//   - tail-tile window over-reads land inside wt3 (same workspace, no fault)
//     and feed only discarded output columns (first OOB pixel 3364 <->
//     first invalid column).
// ---------------------------------------------------------------------------
#define LOADA(dst_, c_)                                                        \
    {                                                                          \
        const int csp_ = (c_) / 18;                                            \
        const int rsk_ = ((c_) % 18) / 2;                                      \
        const int sub_ = (c_) & 1;                                             \
        const u16* ap_ = wt3 + (rsk_ * 4 + csp_) * 16384 + sub_ * 8192;        \
        _Pragma("unroll")                                                      \
        for (int i_ = 0; i_ < 4; i_++)                                         \
            dst_[i_] = *(const short8*)(ap_ + aOff + i_ * 128);                \
    }

__global__ __launch_bounds__(256) void conv_kernel(
        const u16* __restrict__ xq2, const u16* __restrict__ wt3,
        const float* __restrict__ bias, float* __restrict__ out) {
    __shared__ u16 lB[16384];   // [oct(8)][pix(256)][8] window = 32 KB

    const int tid  = threadIdx.x;
    const int lane = tid & 63;
    const int wv   = tid >> 6;
    const int bx   = blockIdx.x;
    const int n    = bx / TILES;
    const int t0   = (bx % TILES) * 128;
    const int k0   = blockIdx.y * 128;

    const int frow = lane & 15;
    const int fkk  = lane >> 4;
    // A-fragment per-lane offset (halves): kc-in-sub = fkk, kout row
    const int aOff = fkk * 2048 + (k0 + (wv >> 1) * 64 + frow) * 8;
    // B-fragment per-lane column base within window
    const int bcol = (wv & 1) * 64 + frow;

    f32x4 acc[4][4] = {};
    short8 a0[4], a1[4], a2[4];          // rotating A banks (chunk k%3)

    // prologue: A for chunks 0,1,2
    LOADA(a0, 0);
    LOADA(a1, 1);
    LOADA(a2, 2);

#pragma unroll
    for (int s = 0; s < 4; s++) {
        __builtin_amdgcn_s_barrier();    // all waves done reading window s-1
        // stage window s: 8 x 1KB contiguous global_load_lds per wave
#pragma unroll
        for (int l = 0; l < 8; l++) {
            const int oct = wv * 2 + (l >> 2);
            const int q   = l & 3;
            __builtin_amdgcn_global_load_lds(
                (glb_u32_t*)(xq2 + ((size_t)(n * 32 + s * 8 + oct) * PP
                                    + t0 + q * 64 + lane) * 8),
                (lds_u32_t*)(lB + oct * 2048 + q * 512 + lane * 8),
                16, 0, 0);
        }
        asm volatile("s_waitcnt vmcnt(0)" ::: "memory");   // window landed
        __builtin_amdgcn_s_barrier();    // ... for ALL waves

#pragma unroll
        for (int k = 0; k < 18; k++) {
            const int c   = 18 * s + k;
            const int rs  = k >> 1;
            const int sub = k & 1;
            const int doff = (rs / 3) * HPAD + (rs % 3);

            // A(c) issued 3 chunks ago; A(c+1),A(c+2) may stay in flight
            if (k >= 3) asm volatile("s_waitcnt vmcnt(8)" ::: "memory");

            short8 bf[4];
#pragma unroll
            for (int j = 0; j < 4; j++)
                bf[j] = *(const short8*)(lB + (sub * 4 + fkk) * 2048
                                         + (doff + bcol + j * 16) * 8);

            __builtin_amdgcn_s_setprio(1);
#pragma unroll
            for (int i = 0; i < 4; i++)
#pragma unroll
                for (int j = 0; j < 4; j++)
                    acc[i][j] = __builtin_amdgcn_mfma_f32_16x16x32_bf16(
                        (k % 3 == 0) ? a0[i] : (k % 3 == 1) ? a1[i] : a2[i],
                        bf[j], acc[i][j], 0, 0, 0);
            __builtin_amdgcn_s_setprio(0);

            if (c + 3 < 72) {            // refill the bank just consumed
                if (k % 3 == 0)      LOADA(a0, c + 3)
                else if (k % 3 == 1) LOADA(a1, c + 3)
                else                 LOADA(a2, c + 3)
            }
        }
    }

    // epilogue: rows = outch, cols = padded pixel t0+col; skip invalid cols
    const int kbase = k0 + (wv >> 1) * 64 + fkk * 4;
    const int mbase = (wv & 1) * 64 + frow;
#pragma unroll
    for (int j = 0; j < 4; j++) {
        int ppp = t0 + mbase + j * 16;
        int h = ppp / HPAD, w = ppp % HPAD;
        if (w < WIMG && h < HIMG) {
            float* ob = out + (size_t)n * KOUT * PIX + h * WIMG + w;
#pragma unroll
            for (int i = 0; i < 4; i++) {
                int kch = kbase + i * 16;
#pragma unroll
                for (int r = 0; r < 4; r++)
                    ob[(size_t)(kch + r) * PIX] = acc[i][j][r] + bias[kch + r];
            }
        }
    }
}

// ---------------------------------------------------------------------------
extern "C" void kernel_launch(void* const* d_in, const int* in_sizes, int n_in,
                              void* d_out, int out_size, void* d_ws, size_t ws_size,
                              hipStream_t stream) {
    const float* x   = (const float*)d_in[0];
    const float* wgt = (const float*)d_in[1];
    const float* bs  = (const float*)d_in[2];
    float* out = (float*)d_out;

    u16* xq2 = (u16*)d_ws;                 // 27.56 MB chunked padded activations
    u16* wt3 = xq2 + XQ_HALVES;            // 1.18 MB  staged weight layout

    quant_fused<<<XBLK + WB, 256, 0, stream>>>(x, xq2, wgt, wt3);
    conv_kernel<<<dim3(NIMG * TILES, 2), 256, 0, stream>>>(xq2, wt3, bs, out);
}